// Round 8
// baseline (32.965 us; speedup 1.0000x reference)
//
#include <hip/hip_runtime.h>

#define NQ 8
#define NL 4
#define NO 16  // = 2*NQ output features

typedef __attribute__((ext_vector_type(4))) float float4v;

// Dense-read variant: each wave covers 64 consecutive rows (16KB contiguous),
// read as two 8x dwordx4 dense tiles; an in-wave shfl gather redistributes
// each row's first 32B to its owning lane pair. Rest = round-5 pipeline.
__global__ __launch_bounds__(256) void qcl_dense(
    const float* __restrict__ x,    // [B,S,64] f32
    const float* __restrict__ rot,  // [NL,NQ,3] f32
    const float* __restrict__ ent,  // [NL,NQ-1] f32
    const float* __restrict__ pw,   // [NO,NQ] f32
    const float* __restrict__ pb,   // [NO] f32
    float* __restrict__ out,        // [B,S,NO] f32
    int n_rows)
{
    __shared__ float sScale[NL][NQ];
    __shared__ float sWl[NL][NQ - 1];
    __shared__ float sW[NO][NQ];
    __shared__ float sB[NO];

    const int tid  = threadIdx.x;
    const int lane = tid & 63;
    const int wglob = blockIdx.x * 4 + (tid >> 6);   // global wave id
    const int R0 = wglob * 64;                       // rows [R0, R0+64)
    const int R1 = R0 + 32;
    const int h    = lane & 1;                       // pair parity
    const int krow = lane >> 1;                      // row within 32-row tile

    const float4v* xb = (const float4v*)x;           // row r = float4 idx [r*16, r*16+16)
    const size_t last4 = (size_t)n_rows * 16 - 1;

    // ---- tile 0: 8 dense dwordx4 loads (32 rows = 8KB contiguous/wave) ----
    float4v s[8];
    #pragma unroll
    for (int i = 0; i < 8; ++i) {
        size_t fidx = (size_t)R0 * 16 + i * 64 + lane;
        if (fidx > last4) fidx = last4;              // clamp (never hit at B*S)
        s[i] = xb[fidx];
    }

    // ---- distributed prologue overlaps load latency ----
    if (tid < NL * NQ) {
        const int l = tid >> 3, q = tid & 7;
        const float r0 = rot[(l * NQ + q) * 3 + 0];
        const float r1 = rot[(l * NQ + q) * 3 + 1];
        const float r2 = rot[(l * NQ + q) * 3 + 2];
        sScale[l][q] = (__cosf(r0) + __sinf(r0)) *
                       (__cosf(r1) + __sinf(r1)) *
                       (__cosf(r2) + __sinf(r2));
    } else if (tid < NL * NQ + NL * (NQ - 1)) {
        const int u = tid - NL * NQ;
        const int l = u / 7, i = u - l * 7;
        const float e = __expf(-ent[l * 7 + i]);
        sWl[l][i] = __builtin_amdgcn_rcpf(1.0f + e);
    } else if (tid >= 64 && tid < 64 + NO) {
        sB[tid - 64] = pb[tid - 64];
    }
    __syncthreads();

    if (tid < NO) {   // W_eff = proj_w * prod_l (E_l D_l)
        float W[NQ];
        #pragma unroll
        for (int q = 0; q < NQ; ++q) W[q] = pw[tid * NQ + q];
        #pragma unroll
        for (int l = NL - 1; l >= 0; --l) {
            float WE[NQ];
            WE[0] = W[0] * (1.0f - sWl[l][0]);
            #pragma unroll
            for (int j = 1; j < NQ - 1; ++j)
                WE[j] = W[j] * (1.0f - sWl[l][j]) + W[j - 1] * sWl[l][j - 1];
            WE[NQ - 1] = W[NQ - 1] + W[NQ - 2] * sWl[l][NQ - 2];
            #pragma unroll
            for (int q = 0; q < NQ; ++q) W[q] = WE[q] * sScale[l][q];
        }
        #pragma unroll
        for (int q = 0; q < NQ; ++q) sW[tid][q] = W[q];
    }
    __syncthreads();

    // gather geometry: lane l's row chunk (krow, h) lives in reg (l>>3) of
    // lane ((l>>1)&3)*16 + h   [tile float4 idx = krow*16 + h = i*64 + ls]
    const int srcLane = ((lane >> 1) & 3) * 16 + h;
    const int myreg = lane >> 3;
    const int base = h * 8;
    const float4v* wrow = (const float4v*)&sW[base][0];

    #pragma unroll
    for (int tt = 0; tt < 2; ++tt) {
        // ---- in-wave gather: 8 rounds x 4 shfl, receiver selects its round ----
        float c0 = 0.f, c1 = 0.f, c2 = 0.f, c3 = 0.f;
        #pragma unroll
        for (int r = 0; r < 8; ++r) {
            float f0 = __shfl(s[r][0], srcLane, 64);
            float f1 = __shfl(s[r][1], srcLane, 64);
            float f2 = __shfl(s[r][2], srcLane, 64);
            float f3 = __shfl(s[r][3], srcLane, 64);
            if (myreg == r) { c0 = f0; c1 = f1; c2 = f2; c3 = f3; }
        }

        // ---- issue tile-1 loads right after s[] is consumed ----
        if (tt == 0) {
            #pragma unroll
            for (int i = 0; i < 8; ++i) {
                size_t fidx = (size_t)R1 * 16 + i * 64 + lane;
                if (fidx > last4) fidx = last4;
                s[i] = xb[fidx];
            }
        }

        // ---- tanh of my 4 values ----
        float m[4], cc[4] = {c0, c1, c2, c3};
        #pragma unroll
        for (int j = 0; j < 4; ++j) {
            float e = __expf(2.0f * cc[j]);
            m[j] = 1.0f - 2.0f * __builtin_amdgcn_rcpf(e + 1.0f);
        }

        // ---- pair exchange: full 8-vector ----
        float t[8];
        #pragma unroll
        for (int j = 0; j < 4; ++j) {
            float o = __shfl_xor(m[j], 1, 64);
            t[j]     = h ? o : m[j];
            t[j + 4] = h ? m[j] : o;
        }

        // ---- matvec: outputs [h*8, h*8+8) ----
        float acc[8];
        #pragma unroll
        for (int j = 0; j < 8; ++j) {
            float4v w0 = wrow[2 * j];
            float4v w1 = wrow[2 * j + 1];
            acc[j] = sB[base + j]
                + w0[0] * t[0] + w0[1] * t[1] + w0[2] * t[2] + w0[3] * t[3]
                + w1[0] * t[4] + w1[1] * t[5] + w1[2] * t[6] + w1[3] * t[7];
        }

        // ---- nontemporal dense store ----
        const int row = (tt == 0 ? R0 : R1) + krow;
        if (row < n_rows) {
            float4v* p = (float4v*)(out + (size_t)row * 16 + base);
            float4v u0 = {acc[0], acc[1], acc[2], acc[3]};
            float4v u1 = {acc[4], acc[5], acc[6], acc[7]};
            __builtin_nontemporal_store(u0, p);
            __builtin_nontemporal_store(u1, p + 1);
        }
    }
}

extern "C" void kernel_launch(void* const* d_in, const int* in_sizes, int n_in,
                              void* d_out, int out_size, void* d_ws, size_t ws_size,
                              hipStream_t stream) {
    const float* x   = (const float*)d_in[0];
    const float* rot = (const float*)d_in[1];
    const float* ent = (const float*)d_in[2];
    const float* pw  = (const float*)d_in[3];
    const float* pb  = (const float*)d_in[4];
    float* out = (float*)d_out;

    const int n_rows = in_sizes[0] / 64;                  // B*S = 524288
    const int waves = (n_rows + 63) / 64;                 // 64 rows per wave
    const int block = 256;
    const int grid = (waves + 3) / 4;                     // 4 waves per block -> 2048
    hipLaunchKernelGGL(qcl_dense, dim3(grid), dim3(block), 0, stream,
                       x, rot, ent, pw, pb, out, n_rows);
}

// Round 9
// 26.880 us; speedup vs baseline: 1.2264x; 1.2264x over previous
//
#include <hip/hip_runtime.h>

#define NQ 8
#define NL 4
#define NO 16  // = 2*NQ output features

typedef __attribute__((ext_vector_type(4))) float float4v;

__global__ __launch_bounds__(256) void qcl_fused(
    const float* __restrict__ x,    // [B,S,64] f32
    const float* __restrict__ rot,  // [NL,NQ,3] f32
    const float* __restrict__ ent,  // [NL,NQ-1] f32
    const float* __restrict__ pw,   // [NO,NQ] f32
    const float* __restrict__ pb,   // [NO] f32
    float* __restrict__ out,        // [B,S,NO] f32
    int n_rows)
{
    __shared__ float sScale[NL][NQ];     // (cos+sin)^3 per (layer,qubit)
    __shared__ float sWl[NL][NQ - 1];    // sigmoid(entangle)
    __shared__ float sW[NO][NQ];         // composed W_eff, row-major 32B rows
    __shared__ float sB[NO];

    const int tid = threadIdx.x;

    // ---- issue global loads FIRST: prologue overlaps their latency ----
    const int nhalf = n_rows * 2;
    const int H = gridDim.x * 256;
    const int gid = blockIdx.x * 256 + tid;
    const int h = tid & 1;
    const int g0 = gid;
    const int g1 = gid + H;
    const bool v0 = g0 < nhalf;
    const bool v1 = g1 < nhalf;

    float4v a0 = {0.f, 0.f, 0.f, 0.f};
    float4v a1 = {0.f, 0.f, 0.f, 0.f};
    if (v0) a0 = *(const float4v*)(x + (size_t)(g0 >> 1) * 64 + h * 4);
    if (v1) a1 = *(const float4v*)(x + (size_t)(g1 >> 1) * 64 + h * 4);

    // ---- distributed prologue: trans ops spread across 60 threads ----
    if (tid < NL * NQ) {                       // 32 threads: one scale each
        const int l = tid >> 3, q = tid & 7;
        const float r0 = rot[(l * NQ + q) * 3 + 0];
        const float r1 = rot[(l * NQ + q) * 3 + 1];
        const float r2 = rot[(l * NQ + q) * 3 + 2];
        sScale[l][q] = (__cosf(r0) + __sinf(r0)) *
                       (__cosf(r1) + __sinf(r1)) *
                       (__cosf(r2) + __sinf(r2));
    } else if (tid < NL * NQ + NL * (NQ - 1)) { // 28 threads: one sigmoid each
        const int u = tid - NL * NQ;
        const int l = u / 7, i = u - l * 7;
        const float e = __expf(-ent[l * 7 + i]);
        sWl[l][i] = __builtin_amdgcn_rcpf(1.0f + e);
    } else if (tid >= 64 && tid < 64 + NO) {    // 16 threads: bias
        sB[tid - 64] = pb[tid - 64];
    }
    __syncthreads();

    if (tid < NO) {   // FMA-only composition: W_eff = proj_w * prod_l (E_l D_l)
        float W[NQ];
        #pragma unroll
        for (int q = 0; q < NQ; ++q) W[q] = pw[tid * NQ + q];
        #pragma unroll
        for (int l = NL - 1; l >= 0; --l) {
            float WE[NQ];
            WE[0] = W[0] * (1.0f - sWl[l][0]);
            #pragma unroll
            for (int j = 1; j < NQ - 1; ++j)
                WE[j] = W[j] * (1.0f - sWl[l][j]) + W[j - 1] * sWl[l][j - 1];
            WE[NQ - 1] = W[NQ - 1] + W[NQ - 2] * sWl[l][NQ - 2];
            #pragma unroll
            for (int q = 0; q < NQ; ++q) W[q] = WE[q] * sScale[l][q];
        }
        #pragma unroll
        for (int q = 0; q < NQ; ++q) sW[tid][q] = W[q];
    }
    __syncthreads();

    if (!v0 && !v1) return;

    // ---- tanh of my 4 values per half-row ----
    float m0[4], m1[4];
    #pragma unroll
    for (int j = 0; j < 4; ++j) {
        float e0 = __expf(2.0f * a0[j]);
        m0[j] = 1.0f - 2.0f * __builtin_amdgcn_rcpf(e0 + 1.0f);
        float e1 = __expf(2.0f * a1[j]);
        m1[j] = 1.0f - 2.0f * __builtin_amdgcn_rcpf(e1 + 1.0f);
    }

    // ---- pair exchange via shfl_xor(1) ----
    float tA[8], tB[8];
    #pragma unroll
    for (int j = 0; j < 4; ++j) {
        float o0 = __shfl_xor(m0[j], 1, 64);
        float o1 = __shfl_xor(m1[j], 1, 64);
        tA[j]     = h ? o0 : m0[j];
        tA[j + 4] = h ? m0[j] : o0;
        tB[j]     = h ? o1 : m1[j];
        tB[j + 4] = h ? m1[j] : o1;
    }

    // ---- matvec: lane computes outputs [h*8, h*8+8) ----
    const int base = h * 8;
    const float4v* wrow = (const float4v*)&sW[base][0];
    float accA[8], accB[8];
    #pragma unroll
    for (int j = 0; j < 8; ++j) {
        float4v w0 = wrow[2 * j];
        float4v w1 = wrow[2 * j + 1];
        float bj = sB[base + j];
        accA[j] = bj + w0.x * tA[0] + w0.y * tA[1] + w0.z * tA[2] + w0.w * tA[3]
                     + w1.x * tA[4] + w1.y * tA[5] + w1.z * tA[6] + w1.w * tA[7];
        accB[j] = bj + w0.x * tB[0] + w0.y * tB[1] + w0.z * tB[2] + w0.w * tB[3]
                     + w1.x * tB[4] + w1.y * tB[5] + w1.z * tB[6] + w1.w * tB[7];
    }

    // ---- TEMPORAL stores: let out's lines live in L2/L3 across graph replays ----
    if (v0) {
        float4v* p = (float4v*)(out + (size_t)(g0 >> 1) * 16 + base);
        float4v u0 = {accA[0], accA[1], accA[2], accA[3]};
        float4v u1 = {accA[4], accA[5], accA[6], accA[7]};
        p[0] = u0; p[1] = u1;
    }
    if (v1) {
        float4v* p = (float4v*)(out + (size_t)(g1 >> 1) * 16 + base);
        float4v u0 = {accB[0], accB[1], accB[2], accB[3]};
        float4v u1 = {accB[4], accB[5], accB[6], accB[7]};
        p[0] = u0; p[1] = u1;
    }
}

extern "C" void kernel_launch(void* const* d_in, const int* in_sizes, int n_in,
                              void* d_out, int out_size, void* d_ws, size_t ws_size,
                              hipStream_t stream) {
    const float* x   = (const float*)d_in[0];
    const float* rot = (const float*)d_in[1];
    const float* ent = (const float*)d_in[2];
    const float* pw  = (const float*)d_in[3];
    const float* pb  = (const float*)d_in[4];
    float* out = (float*)d_out;

    const int n_rows = in_sizes[0] / 64;            // B*S = 524288
    const int nhalf = n_rows * 2;
    const int block = 256;
    const int grid = (nhalf + block * 2 - 1) / (block * 2);  // 2048
    hipLaunchKernelGGL(qcl_fused, dim3(grid), dim3(block), 0, stream,
                       x, rot, ent, pw, pb, out, n_rows);
}

// Round 10
// 26.236 us; speedup vs baseline: 1.2565x; 1.0246x over previous
//
#include <hip/hip_runtime.h>

#define NQ 8
#define NL 4
#define NO 16  // = 2*NQ output features

typedef __attribute__((ext_vector_type(4))) float float4v;

// Collapsed-linear formulation: out = W_eff * tanh(x[:, :8]) + b, where
// W_eff = proj_w * prod_l (E_l D_l) is composed per-block in LDS.
// Pair-split: 2 lanes per row, 2 rows per thread. Measured floor 26.0 us
// (pattern roofline: ~95 MB-eq strided read + 33.5 MB dense write).
__global__ __launch_bounds__(256) void qcl_fused(
    const float* __restrict__ x,    // [B,S,64] f32
    const float* __restrict__ rot,  // [NL,NQ,3] f32
    const float* __restrict__ ent,  // [NL,NQ-1] f32
    const float* __restrict__ pw,   // [NO,NQ] f32
    const float* __restrict__ pb,   // [NO] f32
    float* __restrict__ out,        // [B,S,NO] f32
    int n_rows)
{
    __shared__ float sScale[NL][NQ];     // (cos+sin)^3 per (layer,qubit)
    __shared__ float sWl[NL][NQ - 1];    // sigmoid(entangle)
    __shared__ float sW[NO][NQ];         // composed W_eff, row-major 32B rows
    __shared__ float sB[NO];

    const int tid = threadIdx.x;

    // ---- issue global loads FIRST: prologue overlaps their latency ----
    const int nhalf = n_rows * 2;
    const int H = gridDim.x * 256;
    const int gid = blockIdx.x * 256 + tid;
    const int h = tid & 1;
    const int g0 = gid;
    const int g1 = gid + H;
    const bool v0 = g0 < nhalf;
    const bool v1 = g1 < nhalf;

    float4v a0 = {0.f, 0.f, 0.f, 0.f};
    float4v a1 = {0.f, 0.f, 0.f, 0.f};
    if (v0) a0 = *(const float4v*)(x + (size_t)(g0 >> 1) * 64 + h * 4);
    if (v1) a1 = *(const float4v*)(x + (size_t)(g1 >> 1) * 64 + h * 4);

    // ---- distributed prologue: trans ops spread across 60 threads ----
    if (tid < NL * NQ) {                       // 32 threads: one scale each
        const int l = tid >> 3, q = tid & 7;
        const float r0 = rot[(l * NQ + q) * 3 + 0];
        const float r1 = rot[(l * NQ + q) * 3 + 1];
        const float r2 = rot[(l * NQ + q) * 3 + 2];
        sScale[l][q] = (__cosf(r0) + __sinf(r0)) *
                       (__cosf(r1) + __sinf(r1)) *
                       (__cosf(r2) + __sinf(r2));
    } else if (tid < NL * NQ + NL * (NQ - 1)) { // 28 threads: one sigmoid each
        const int u = tid - NL * NQ;
        const int l = u / 7, i = u - l * 7;
        const float e = __expf(-ent[l * 7 + i]);
        sWl[l][i] = __builtin_amdgcn_rcpf(1.0f + e);
    } else if (tid >= 64 && tid < 64 + NO) {    // 16 threads: bias
        sB[tid - 64] = pb[tid - 64];
    }
    __syncthreads();

    if (tid < NO) {   // FMA-only composition: W_eff = proj_w * prod_l (E_l D_l)
        float W[NQ];
        #pragma unroll
        for (int q = 0; q < NQ; ++q) W[q] = pw[tid * NQ + q];
        #pragma unroll
        for (int l = NL - 1; l >= 0; --l) {
            float WE[NQ];
            WE[0] = W[0] * (1.0f - sWl[l][0]);
            #pragma unroll
            for (int j = 1; j < NQ - 1; ++j)
                WE[j] = W[j] * (1.0f - sWl[l][j]) + W[j - 1] * sWl[l][j - 1];
            WE[NQ - 1] = W[NQ - 1] + W[NQ - 2] * sWl[l][NQ - 2];
            #pragma unroll
            for (int q = 0; q < NQ; ++q) W[q] = WE[q] * sScale[l][q];
        }
        #pragma unroll
        for (int q = 0; q < NQ; ++q) sW[tid][q] = W[q];
    }
    __syncthreads();

    if (!v0 && !v1) return;

    // ---- tanh of my 4 values per half-row ----
    float m0[4], m1[4];
    #pragma unroll
    for (int j = 0; j < 4; ++j) {
        float e0 = __expf(2.0f * a0[j]);
        m0[j] = 1.0f - 2.0f * __builtin_amdgcn_rcpf(e0 + 1.0f);
        float e1 = __expf(2.0f * a1[j]);
        m1[j] = 1.0f - 2.0f * __builtin_amdgcn_rcpf(e1 + 1.0f);
    }

    // ---- pair exchange via shfl_xor(1) ----
    float tA[8], tB[8];
    #pragma unroll
    for (int j = 0; j < 4; ++j) {
        float o0 = __shfl_xor(m0[j], 1, 64);
        float o1 = __shfl_xor(m1[j], 1, 64);
        tA[j]     = h ? o0 : m0[j];
        tA[j + 4] = h ? m0[j] : o0;
        tB[j]     = h ? o1 : m1[j];
        tB[j + 4] = h ? m1[j] : o1;
    }

    // ---- matvec: lane computes outputs [h*8, h*8+8) ----
    const int base = h * 8;
    const float4v* wrow = (const float4v*)&sW[base][0];
    float accA[8], accB[8];
    #pragma unroll
    for (int j = 0; j < 8; ++j) {
        float4v w0 = wrow[2 * j];
        float4v w1 = wrow[2 * j + 1];
        float bj = sB[base + j];
        accA[j] = bj + w0.x * tA[0] + w0.y * tA[1] + w0.z * tA[2] + w0.w * tA[3]
                     + w1.x * tA[4] + w1.y * tA[5] + w1.z * tA[6] + w1.w * tA[7];
        accB[j] = bj + w0.x * tB[0] + w0.y * tB[1] + w0.z * tB[2] + w0.w * tB[3]
                     + w1.x * tB[4] + w1.y * tB[5] + w1.z * tB[6] + w1.w * tB[7];
    }

    // ---- nontemporal dense stores (measured best: 26.0 vs 26.9 temporal) ----
    if (v0) {
        float4v* p = (float4v*)(out + (size_t)(g0 >> 1) * 16 + base);
        float4v u0 = {accA[0], accA[1], accA[2], accA[3]};
        float4v u1 = {accA[4], accA[5], accA[6], accA[7]};
        __builtin_nontemporal_store(u0, p);
        __builtin_nontemporal_store(u1, p + 1);
    }
    if (v1) {
        float4v* p = (float4v*)(out + (size_t)(g1 >> 1) * 16 + base);
        float4v u0 = {accB[0], accB[1], accB[2], accB[3]};
        float4v u1 = {accB[4], accB[5], accB[6], accB[7]};
        __builtin_nontemporal_store(u0, p);
        __builtin_nontemporal_store(u1, p + 1);
    }
}

extern "C" void kernel_launch(void* const* d_in, const int* in_sizes, int n_in,
                              void* d_out, int out_size, void* d_ws, size_t ws_size,
                              hipStream_t stream) {
    const float* x   = (const float*)d_in[0];
    const float* rot = (const float*)d_in[1];
    const float* ent = (const float*)d_in[2];
    const float* pw  = (const float*)d_in[3];
    const float* pb  = (const float*)d_in[4];
    float* out = (float*)d_out;

    const int n_rows = in_sizes[0] / 64;            // B*S = 524288
    const int nhalf = n_rows * 2;
    const int block = 256;
    const int grid = (nhalf + block * 2 - 1) / (block * 2);  // 2048
    hipLaunchKernelGGL(qcl_fused, dim3(grid), dim3(block), 0, stream,
                       x, rot, ent, pw, pb, out, n_rows);
}